// Round 3
// baseline (844.987 us; speedup 1.0000x reference)
//
#include <hip/hip_runtime.h>
#include <hip/hip_bf16.h>

#define NN 50000
#define NE 800000
#define D 128
#define ED 64
#define IN_DIM 320
#define MB 64            // edges per tile
#define KP 328           // padded LDS row (ushorts)
#define NT (NE / MB)     // 12500 tiles
#define PGRID 768        // persistent grid: 3 blocks/CU * 256 CU

typedef short short8 __attribute__((ext_vector_type(8)));
typedef float f32x4 __attribute__((ext_vector_type(4)));

__device__ __forceinline__ ushort f2b(float f) {
  __hip_bfloat16 h = __float2bfloat16(f);
  return *reinterpret_cast<ushort*>(&h);
}

__device__ __forceinline__ ushort4 c4(float4 v) {
  ushort4 u; u.x = f2b(v.x); u.y = f2b(v.y); u.z = f2b(v.z); u.w = f2b(v.w);
  return u;
}

// gather one tile's x into bf16 registers; 4 threads per edge, 20 x ushort4
__device__ __forceinline__ void gather_regs(
    ushort4 g[20], const int* __restrict__ senders,
    const int* __restrict__ receivers, const float* __restrict__ nodes,
    const float* __restrict__ efeat, int e0, int tid)
{
  const int e = tid >> 2, p = tid & 3;
  const float* ns = nodes + (size_t)senders[e0 + e] * D;
  const float* nr = nodes + (size_t)receivers[e0 + e] * D;
  const float* ef = efeat + (size_t)(e0 + e) * ED;
#pragma unroll
  for (int i = 0; i < 8; ++i) g[i] = c4(*(const float4*)(ns + (p + 4 * i) * 4));
#pragma unroll
  for (int i = 0; i < 8; ++i) g[8 + i] = c4(*(const float4*)(nr + (p + 4 * i) * 4));
#pragma unroll
  for (int i = 0; i < 4; ++i) g[16 + i] = c4(*(const float4*)(ef + (p + 4 * i) * 4));
}

__device__ __forceinline__ void write_xs(
    ushort xs[MB][KP], const ushort4 g[20], int tid)
{
  const int e = tid >> 2, p = tid & 3;
#pragma unroll
  for (int i = 0; i < 8; ++i)
    *reinterpret_cast<ushort4*>(&xs[e][(p + 4 * i) * 4]) = g[i];
#pragma unroll
  for (int i = 0; i < 8; ++i)
    *reinterpret_cast<ushort4*>(&xs[e][128 + (p + 4 * i) * 4]) = g[8 + i];
#pragma unroll
  for (int i = 0; i < 4; ++i)
    *reinterpret_cast<ushort4*>(&xs[e][256 + (p + 4 * i) * 4]) = g[16 + i];
}

// ---------------- weight transpose + bf16 convert ---------------------------
__global__ __launch_bounds__(256) void k_wconv(
    const float* __restrict__ Wq, const float* __restrict__ W1,
    ushort* __restrict__ Wqt, ushort* __restrict__ W1t)
{
  int i = blockIdx.x * 256 + threadIdx.x;
  if (i < D * IN_DIM) {
    int n = i / IN_DIM, k = i - n * IN_DIM;
    Wqt[i] = f2b(Wq[k * D + n]);
    W1t[i] = f2b(W1[k * D + n]);
  }
}

// ---------------- pass 1: logits + segment max (persistent) -----------------
__global__ __launch_bounds__(256, 3) void k_logits(
    const float* __restrict__ nodes,
    const int* __restrict__ senders, const int* __restrict__ receivers,
    const float* __restrict__ efeat,
    const ushort* __restrict__ W1t, const float* __restrict__ b1,
    const float* __restrict__ gamma_, const float* __restrict__ beta_,
    const float* __restrict__ W2, const float* __restrict__ b2,
    float* __restrict__ logits, float* __restrict__ seg_max)
{
  __shared__ ushort xs[MB][KP];
  __shared__ float red[MB][4][2];
  __shared__ float fin[MB][2];
  __shared__ float dred[MB][4];
  const int tid = threadIdx.x;
  const int w = tid >> 6, l = tid & 63, lr = l & 15, lg = l >> 4;
  const int n0 = (2 * w) * 16 + lr, n1 = (2 * w + 1) * 16 + lr;

  const float b1a = b1[n0], b1b = b1[n1];
  const float g0 = gamma_[n0], g1 = gamma_[n1];
  const float be0 = beta_[n0], be1 = beta_[n1];
  const float w20 = W2[n0], w21 = W2[n1];
  const float b2s = b2[0];

  int tile = blockIdx.x;
  ushort4 g[20];
  gather_regs(g, senders, receivers, nodes, efeat, tile * MB, tid);

  while (tile < NT) {
    const int e0 = tile * MB;
    write_xs(xs, g, tid);
    __syncthreads();                           // xs ready

    const int nxt = tile + PGRID;
    if (nxt < NT)
      gather_regs(g, senders, receivers, nodes, efeat, nxt * MB, tid);

    f32x4 acc[4][2] = {};
#pragma unroll
    for (int ks = 0; ks < 10; ++ks) {
      short8 B0 = *reinterpret_cast<const short8*>(W1t + n0 * IN_DIM + ks * 32 + lg * 8);
      short8 B1 = *reinterpret_cast<const short8*>(W1t + n1 * IN_DIM + ks * 32 + lg * 8);
      short8 A[4];
#pragma unroll
      for (int mt = 0; mt < 4; ++mt)
        A[mt] = *reinterpret_cast<const short8*>(&xs[mt * 16 + lr][ks * 32 + lg * 8]);
#pragma unroll
      for (int mt = 0; mt < 4; ++mt) {
        acc[mt][0] = __builtin_amdgcn_mfma_f32_16x16x32_bf16(A[mt], B0, acc[mt][0], 0, 0, 0);
        acc[mt][1] = __builtin_amdgcn_mfma_f32_16x16x32_bf16(A[mt], B1, acc[mt][1], 0, 0, 0);
      }
    }

    // bias + ReLU, LN stats across 128 cols
#pragma unroll
    for (int mt = 0; mt < 4; ++mt)
#pragma unroll
      for (int r = 0; r < 4; ++r) {
        acc[mt][0][r] = fmaxf(acc[mt][0][r] + b1a, 0.f);
        acc[mt][1][r] = fmaxf(acc[mt][1][r] + b1b, 0.f);
      }
#pragma unroll
    for (int mt = 0; mt < 4; ++mt)
#pragma unroll
      for (int r = 0; r < 4; ++r) {
        float s = acc[mt][0][r] + acc[mt][1][r];
        float q = acc[mt][0][r] * acc[mt][0][r] + acc[mt][1][r] * acc[mt][1][r];
#pragma unroll
        for (int off = 1; off < 16; off <<= 1) {
          s += __shfl_xor(s, off);
          q += __shfl_xor(q, off);
        }
        if (lr == mt * 4 + r) {
          red[mt * 16 + lg * 4 + r][w][0] = s;
          red[mt * 16 + lg * 4 + r][w][1] = q;
        }
      }
    __syncthreads();                           // red ready
    if (tid < MB) {
      float s = red[tid][0][0] + red[tid][1][0] + red[tid][2][0] + red[tid][3][0];
      float q = red[tid][0][1] + red[tid][1][1] + red[tid][2][1] + red[tid][3][1];
      float mu = s * (1.f / 128.f);
      float var = fmaxf(q * (1.f / 128.f) - mu * mu, 0.f);
      fin[tid][0] = mu;
      fin[tid][1] = rsqrtf(var + 1e-5f);
    }
    __syncthreads();                           // fin ready

#pragma unroll
    for (int mt = 0; mt < 4; ++mt)
#pragma unroll
      for (int r = 0; r < 4; ++r) {
        int row = mt * 16 + lg * 4 + r;
        float mu = fin[row][0], rs = fin[row][1];
        float h0 = (acc[mt][0][r] - mu) * rs * g0 + be0;
        float h1 = (acc[mt][1][r] - mu) * rs * g1 + be1;
        float dv = h0 * w20 + h1 * w21;
#pragma unroll
        for (int off = 1; off < 16; off <<= 1) dv += __shfl_xor(dv, off);
        if (lr == mt * 4 + r) dred[row][w] = dv;
      }
    __syncthreads();                           // dred ready
    if (tid < MB) {
      float dv = dred[tid][0] + dred[tid][1] + dred[tid][2] + dred[tid][3] + b2s;
      float logit = fmaxf(dv, 0.f);
      logits[e0 + tid] = logit;
      atomicMax((int*)&seg_max[receivers[e0 + tid]], __float_as_int(logit));
    }
    tile = nxt;
  }
}

// ---------------- pass 2: exp + segment sum ---------------------------------
__global__ __launch_bounds__(256) void k_exp(
    const float* __restrict__ logits, const int* __restrict__ receivers,
    const float* __restrict__ seg_max, float* __restrict__ exp_l,
    float* __restrict__ seg_sum)
{
  int i = blockIdx.x * 256 + threadIdx.x;
  if (i < NE) {
    int r = receivers[i];
    float ex = expf(logits[i] - seg_max[r]);
    exp_l[i] = ex;
    atomicAdd(&seg_sum[r], ex);
  }
}

// ---------------- pass 3: queries * weight, scatter-add (persistent) --------
__global__ __launch_bounds__(256, 3) void k_scatter(
    const float* __restrict__ nodes,
    const int* __restrict__ senders, const int* __restrict__ receivers,
    const float* __restrict__ efeat,
    const ushort* __restrict__ Wqt, const float* __restrict__ bq,
    const float* __restrict__ exp_l, const float* __restrict__ seg_sum,
    float* __restrict__ accum)
{
  __shared__ ushort xs[MB][KP];
  __shared__ float wrow[MB];
  __shared__ int rr[MB];
  const int tid = threadIdx.x;
  const int w = tid >> 6, l = tid & 63, lr = l & 15, lg = l >> 4;
  const int n0 = (2 * w) * 16 + lr, n1 = (2 * w + 1) * 16 + lr;
  const float bq0 = bq[n0], bq1 = bq[n1];

  int tile = blockIdx.x;
  ushort4 g[20];
  gather_regs(g, senders, receivers, nodes, efeat, tile * MB, tid);

  while (tile < NT) {
    const int e0 = tile * MB;
    write_xs(xs, g, tid);
    if (tid < MB) {
      int r = receivers[e0 + tid];
      rr[tid] = r;
      wrow[tid] = exp_l[e0 + tid] / (seg_sum[r] + 1e-10f);
    }
    __syncthreads();                           // xs + wrow ready

    const int nxt = tile + PGRID;
    if (nxt < NT)
      gather_regs(g, senders, receivers, nodes, efeat, nxt * MB, tid);

    f32x4 acc[4][2] = {};
#pragma unroll
    for (int ks = 0; ks < 10; ++ks) {
      short8 B0 = *reinterpret_cast<const short8*>(Wqt + n0 * IN_DIM + ks * 32 + lg * 8);
      short8 B1 = *reinterpret_cast<const short8*>(Wqt + n1 * IN_DIM + ks * 32 + lg * 8);
      short8 A[4];
#pragma unroll
      for (int mt = 0; mt < 4; ++mt)
        A[mt] = *reinterpret_cast<const short8*>(&xs[mt * 16 + lr][ks * 32 + lg * 8]);
#pragma unroll
      for (int mt = 0; mt < 4; ++mt) {
        acc[mt][0] = __builtin_amdgcn_mfma_f32_16x16x32_bf16(A[mt], B0, acc[mt][0], 0, 0, 0);
        acc[mt][1] = __builtin_amdgcn_mfma_f32_16x16x32_bf16(A[mt], B1, acc[mt][1], 0, 0, 0);
      }
    }

#pragma unroll
    for (int mt = 0; mt < 4; ++mt)
#pragma unroll
      for (int r = 0; r < 4; ++r) {
        int row = mt * 16 + lg * 4 + r;
        float wt_ = wrow[row];
        size_t base = (size_t)rr[row] * D;
        atomicAdd(&accum[base + n0], (acc[mt][0][r] + bq0) * wt_);
        atomicAdd(&accum[base + n1], (acc[mt][1][r] + bq1) * wt_);
      }
    __syncthreads();                           // protect wrow/rr for next tile
    tile = nxt;
  }
}

// ---------------- pass 4: leaky relu ----------------------------------------
__global__ __launch_bounds__(256) void k_final(
    const float* __restrict__ accum, float* __restrict__ out)
{
  int i = blockIdx.x * 256 + threadIdx.x;
  if (i < NN * D) {
    float v = accum[i];
    out[i] = v > 0.f ? v : 0.01f * v;
  }
}

extern "C" void kernel_launch(void* const* d_in, const int* in_sizes, int n_in,
                              void* d_out, int out_size, void* d_ws, size_t ws_size,
                              hipStream_t stream) {
  const float* nodes  = (const float*)d_in[0];
  const int*   eidx   = (const int*)d_in[1];
  const float* efeat  = (const float*)d_in[2];
  const float* Wq     = (const float*)d_in[3];
  const float* bq     = (const float*)d_in[4];
  const float* W1     = (const float*)d_in[5];
  const float* b1     = (const float*)d_in[6];
  const float* gamma_ = (const float*)d_in[7];
  const float* beta_  = (const float*)d_in[8];
  const float* W2     = (const float*)d_in[9];
  const float* b2     = (const float*)d_in[10];
  const int* senders   = eidx;
  const int* receivers = eidx + NE;

  float* ws      = (float*)d_ws;
  float* logits  = ws;                  // NE
  float* exp_l   = ws + NE;             // NE
  float* seg_max = ws + 2 * NE;         // NN
  float* seg_sum = seg_max + NN;        // NN
  float* accum   = seg_sum + NN;        // NN*D
  ushort* Wqt    = (ushort*)(accum + (size_t)NN * D);  // 128*320
  ushort* W1t    = Wqt + D * IN_DIM;                   // 128*320

  hipMemsetAsync(seg_max, 0, NN * sizeof(float), stream);
  hipMemsetAsync(seg_sum, 0, NN * sizeof(float), stream);
  hipMemsetAsync(accum, 0, (size_t)NN * D * sizeof(float), stream);

  k_wconv<<<(D * IN_DIM + 255) / 256, 256, 0, stream>>>(Wq, W1, Wqt, W1t);
  k_logits<<<PGRID, 256, 0, stream>>>(nodes, senders, receivers, efeat,
                                      W1t, b1, gamma_, beta_, W2, b2,
                                      logits, seg_max);
  k_exp<<<(NE + 255) / 256, 256, 0, stream>>>(logits, receivers, seg_max,
                                              exp_l, seg_sum);
  k_scatter<<<PGRID, 256, 0, stream>>>(nodes, senders, receivers, efeat,
                                       Wqt, bq, exp_l, seg_sum, accum);
  k_final<<<(NN * D + 255) / 256, 256, 0, stream>>>(accum, (float*)d_out);
}